// Round 5
// baseline (53.855 us; speedup 1.0000x reference)
//
#include <hip/hip_runtime.h>

// 2D Gaussian splatting renderer, MI355X. R8.
// N=4096 gaussians, 512x512x3 fp32 image, 64 tiles of 64x64 px.
//
// R8 theory: 3-kernel chains cost +10us (R4 47.9, R7 47.5 vs R5 37.4) ->
// stay 2-kernel. R5 render is LDS-broadcast-bound: per-CU LDS cyc =
// waves-per-list x iters x 30; P=2 => 768k wave-iters => 37us (verified by
// R6 VALUBusy calibration: sum of tile totals ~24k). Fix: P=4 px/lane in
// 128-thread blocks, 512 blocks (8 blocks/tile, 2 waves each, 2 blocks/CU
// for heavy/light tile mixing). LDS halves to ~18.7us; VALU ~13.8us;
// heavy-tile wave critical path ~22us => render ~22-25us, chain ~28-32us.
// Per-pixel FP sequence identical to R5.

#define N_G    4096
#define W_IMG  512
#define TL_    64
#define NTILES 64
#define CHUNK  256
#define LOG2E  1.44269504088896340736f

// ws layout (bytes):
//   [0,      65536) : float4 a4[N_G] = {px, py, qa, qb}   (depth-sorted)
//                     qa = -0.5*ia*log2e, qb = -0.5*ibc*log2e
//   [65536, 131072) : float4 b4[N_G] = {qc, lb, cr, cg}
//                     qc = -0.5*idd*log2e, lb = log2(op)
//   [131072,147456) : float  c1[N_G]  = cb
//   [147456,180224) : u64    tmask[N_G] = tile-overlap bitmask (bit tx*8+ty)

__global__ __launch_bounds__(256)
void gs_preprocess(const float* __restrict__ pos2d,
                   const float* __restrict__ cov2d,
                   const float* __restrict__ opacity,
                   const float* __restrict__ color,
                   float4* __restrict__ a4,
                   float4* __restrict__ b4,
                   float* __restrict__ c1,
                   unsigned long long* __restrict__ tmask) {
    __shared__ __align__(16) float s_depth[N_G];
    const int t = threadIdx.x;

    for (int k = t; k < N_G; k += 256)
        s_depth[k] = pos2d[k * 3 + 2];
    __syncthreads();

    const int g = t >> 5;                  // 8 gaussian slots per block
    const int s = t & 31;                  // 32-way j partition per gaussian
    const int i = blockIdx.x * 8 + g;      // 512 blocks x 8 = 4096
    const float di = s_depth[i];

    const float4* s_d4 = (const float4*)s_depth;
    int rank = 0;
    #pragma unroll 8
    for (int k = 0; k < 32; ++k) {
        const int j4 = s + 32 * k;
        const float4 d = s_d4[j4];
        const int j = 4 * j4;
        rank += (d.x < di) || (d.x == di && (j + 0) < i);   // stable argsort
        rank += (d.y < di) || (d.y == di && (j + 1) < i);
        rank += (d.z < di) || (d.z == di && (j + 2) < i);
        rank += (d.w < di) || (d.w == di && (j + 3) < i);
    }
    rank += __shfl_xor(rank, 1);
    rank += __shfl_xor(rank, 2);
    rank += __shfl_xor(rank, 4);
    rank += __shfl_xor(rank, 8);
    rank += __shfl_xor(rank, 16);

    if (s == 0) {
        const float px = pos2d[i * 3 + 0];
        const float py = pos2d[i * 3 + 1];
        const float a = cov2d[i * 4 + 0];
        const float b = cov2d[i * 4 + 1];
        const float c = cov2d[i * 4 + 2];
        const float d = cov2d[i * 4 + 3];

        const float trace = a + d;
        const float det = a * d - b * c;
        const float tmp = trace * trace - 4.0f * det;
        const float term2 = 0.5f * sqrtf(fmaxf(tmp, 0.0f));
        const float radius = 3.0f * sqrtf(fmaxf(0.5f * trace - term2, 0.5f * trace + term2));
        const float inv_det = 1.0f / det;
        const float ia  = d * inv_det;
        const float ibc = (-b * inv_det) + (-c * inv_det);  // match ref's ib+ic rounding
        const float idd = a * inv_det;

        const float op = opacity[i];
        const float cr = fmaxf(color[i * 3 + 0] + 0.5f, 0.0f);
        const float cg = fmaxf(color[i * 3 + 1] + 0.5f, 0.0f);
        const float cb = fmaxf(color[i * 3 + 2] + 0.5f, 0.0f);

        // Tile-overlap bitmask, bit (tx*8+ty); comparisons IDENTICAL to the
        // reference cull so the listed set matches exactly.
        unsigned int xm = 0, ym = 0;
        #pragma unroll
        for (int tc = 0; tc < 8; ++tc) {
            const float lo = (float)(tc * TL_);
            if ((px + radius >= lo) && (px - radius < lo + (float)TL_)) xm |= 1u << tc;
            if ((py + radius >= lo) && (py - radius < lo + (float)TL_)) ym |= 1u << tc;
        }
        unsigned long long m = 0ull;
        #pragma unroll
        for (int tc = 0; tc < 8; ++tc)
            if (xm & (1u << tc)) m |= (unsigned long long)ym << (8 * tc);

        a4[rank] = make_float4(px, py, -0.5f * ia * LOG2E, -0.5f * ibc * LOG2E);
        b4[rank] = make_float4(-0.5f * idd * LOG2E, __log2f(op), cr, cg);
        c1[rank] = cb;
        tmask[rank] = m;
    }
}

__global__ __launch_bounds__(128)
void gs_render(const float4* __restrict__ a4,
               const float4* __restrict__ b4,
               const float* __restrict__ c1,
               const unsigned long long* __restrict__ tmask,
               float* __restrict__ out) {
    // 512 blocks x 128 threads, 4 px/thread. 8 blocks/tile (sub 0..7),
    // scrambled tile map so the 2 co-resident blocks per CU come from
    // different tiles. Block covers 8 px in X (2 waves x 4), 64 in Y.
    __shared__ unsigned short s_list[N_G];
    __shared__ int s_wcnt[2];
    __shared__ __align__(16) float4 s_a[CHUNK];
    __shared__ __align__(16) float4 s_b[CHUNK];
    __shared__ float s_c[CHUNK];

    const int id = blockIdx.x;
    const int sub  = id >> 6;              // 0..7
    const int tile = ((id & 63) * 21 + sub * 11) & 63;
    const int tx = tile >> 3;
    const int ty = tile & 7;
    const int t = threadIdx.x;
    const int wave = t >> 6;               // 0..1
    const int lane = t & 63;

    // ---- cull via tile mask: 2-pass cross-wave-stable compaction, wave w
    //      owns g in [w*2048,(w+1)*2048) so concatenated segments stay
    //      depth-ordered.
    unsigned int bits = 0;
    int wcnt = 0;
    #pragma unroll 4
    for (int it = 0; it < 32; ++it) {
        const int g = wave * 2048 + it * 64 + lane;
        const bool m = (tmask[g] >> tile) & 1ull;
        bits |= (m ? 1u : 0u) << it;
        wcnt += __popcll(__ballot(m));
    }
    if (lane == 0) s_wcnt[wave] = wcnt;
    __syncthreads();
    const int c0 = s_wcnt[0];
    const int total = c0 + s_wcnt[1];
    int base = wave > 0 ? c0 : 0;
    #pragma unroll 4
    for (int it = 0; it < 32; ++it) {
        const bool m = (bits >> it) & 1u;
        const unsigned long long bal = __ballot(m);
        const int prefix = __popcll(bal & ((1ULL << lane) - 1ULL));
        if (m) s_list[base + prefix] = (unsigned short)(wave * 2048 + it * 64 + lane);
        base += __popcll(bal);
    }
    // barrier before first s_list read is the chunk-loop-top __syncthreads

    const int X0 = tx * TL_ + sub * 8 + wave * 4;
    const int Y  = ty * TL_ + lane;
    const float fX = (float)X0;
    const float fY = (float)Y;

    float T0 = 1.f, T1 = 1.f, T2 = 1.f, T3 = 1.f;
    float R0 = 0.f, G0 = 0.f, B0 = 0.f;
    float R1 = 0.f, G1 = 0.f, B1 = 0.f;
    float R2 = 0.f, G2 = 0.f, B2 = 0.f;
    float R3 = 0.f, G3 = 0.f, B3 = 0.f;

    for (int cb_ = 0; cb_ < total; cb_ += CHUNK) {
        __syncthreads();   // protect s_list (1st iter) / s_a,s_b,s_c (reuse)
        #pragma unroll 2
        for (int j = t; j < CHUNK; j += 128) {
            const int gi = cb_ + j;
            if (gi < total) {
                const int g = s_list[gi];
                s_a[j] = a4[g];
                s_b[j] = b4[g];
                s_c[j] = c1[g];
            }
        }
        __syncthreads();

        const int n = min(CHUNK, total - cb_);
        #pragma unroll 4
        for (int k = 0; k < n; ++k) {
            const float4 A  = s_a[k];   // px, py, qa, qb
            const float4 Bv = s_b[k];   // qc, lb, cr, cg
            const float cbv = s_c[k];
            const float dy   = fY - A.y;
            const float qbdy = A.w * dy;
            const float bse  = Bv.x * dy * dy + Bv.y;        // qc*dy^2 + lb
            const float dx0  = fX - A.x;
#define PX_BLEND(i, T, Rr, Gg, Bb)                                            \
            {                                                                 \
                const float dx = dx0 + (float)i;                              \
                const float q = (A.z * dx + qbdy) * dx + bse;                 \
                const float e = exp2f(q);                                     \
                const float alpha = __builtin_amdgcn_fmed3f(e, 0.01f, 0.99f); \
                const float w_ = alpha * T;                                   \
                Rr += w_ * Bv.z; Gg += w_ * Bv.w; Bb += w_ * cbv;             \
                T -= w_;                                                      \
            }
            PX_BLEND(0, T0, R0, G0, B0)
            PX_BLEND(1, T1, R1, G1, B1)
            PX_BLEND(2, T2, R2, G2, B2)
            PX_BLEND(3, T3, R3, G3, B3)
#undef PX_BLEND
        }
    }

    const int o0 = (X0 * W_IMG + Y) * 3;
    out[o0 + 0] = R0; out[o0 + 1] = G0; out[o0 + 2] = B0;
    out[o0 + 1 * W_IMG * 3 + 0] = R1; out[o0 + 1 * W_IMG * 3 + 1] = G1; out[o0 + 1 * W_IMG * 3 + 2] = B1;
    out[o0 + 2 * W_IMG * 3 + 0] = R2; out[o0 + 2 * W_IMG * 3 + 1] = G2; out[o0 + 2 * W_IMG * 3 + 2] = B2;
    out[o0 + 3 * W_IMG * 3 + 0] = R3; out[o0 + 3 * W_IMG * 3 + 1] = G3; out[o0 + 3 * W_IMG * 3 + 2] = B3;
}

extern "C" void kernel_launch(void* const* d_in, const int* in_sizes, int n_in,
                              void* d_out, int out_size, void* d_ws, size_t ws_size,
                              hipStream_t stream) {
    const float* pos2d   = (const float*)d_in[0];
    const float* cov2d   = (const float*)d_in[1];
    const float* opacity = (const float*)d_in[2];
    const float* color   = (const float*)d_in[3];
    float* out = (float*)d_out;

    char* ws = (char*)d_ws;
    float4* a4 = (float4*)(ws);
    float4* b4 = (float4*)(ws + 65536);
    float*  c1 = (float*)(ws + 131072);
    unsigned long long* tm = (unsigned long long*)(ws + 147456);

    gs_preprocess<<<N_G / 8, 256, 0, stream>>>(pos2d, cov2d, opacity, color,
                                               a4, b4, c1, tm);
    gs_render<<<512, 128, 0, stream>>>(a4, b4, c1, tm, out);
}

// Round 6
// 39.651 us; speedup vs baseline: 1.3582x; 1.3582x over previous
//
#include <hip/hip_runtime.h>

// 2D Gaussian splatting renderer, MI355X. R9.
// N=4096 gaussians, 512x512x3 fp32 image, 64 tiles of 64x64 px.
//
// R9 theory: two confirmed cost terms: (1) LDS-broadcast pipe cyc/CU =
// wave-iters x 30 / 256CU, wave-iters = px-waves-per-list x list-len (R5:
// 657k -> 32us render; R8: 328k but regressed); (2) latency hiding needs
// >=8 waves/CU (R8 at 1 wave/SIMD: VALUBusy 28.5%, occupancy 6.4%, 42.6us).
// Fix: keep P=4 (halves LDS traffic) AND 8 waves/CU by splitting each
// tile's depth list into 2 segments processed by different waves of the
// SAME 256-thread block (blend is associative: C = C_A + T_A*C_B,
// T = T_A*T_B), merged once via LDS at the end. 512 blocks x 256 thr,
// waves 0-1 = 8 px-cols x seg0, waves 2-3 = same px x seg1.
// Model: LDS 328k x 30/256 = 38k cyc ~ 16us; VALU ~13us; render ~16-20us.

#define N_G    4096
#define W_IMG  512
#define TL_    64
#define NTILES 64
#define CHUNK  256
#define LOG2E  1.44269504088896340736f

// ws layout (bytes):
//   [0,      65536) : float4 a4[N_G] = {px, py, qa, qb}   (depth-sorted)
//                     qa = -0.5*ia*log2e, qb = -0.5*ibc*log2e
//   [65536, 131072) : float4 b4[N_G] = {qc, lb, cr, cg}
//                     qc = -0.5*idd*log2e, lb = log2(op)
//   [131072,147456) : float  c1[N_G]  = cb
//   [147456,180224) : u64    tmask[N_G] = tile-overlap bitmask (bit tx*8+ty)

__global__ __launch_bounds__(256)
void gs_preprocess(const float* __restrict__ pos2d,
                   const float* __restrict__ cov2d,
                   const float* __restrict__ opacity,
                   const float* __restrict__ color,
                   float4* __restrict__ a4,
                   float4* __restrict__ b4,
                   float* __restrict__ c1,
                   unsigned long long* __restrict__ tmask) {
    __shared__ __align__(16) float s_depth[N_G];
    const int t = threadIdx.x;

    for (int k = t; k < N_G; k += 256)
        s_depth[k] = pos2d[k * 3 + 2];
    __syncthreads();

    const int g = t >> 5;                  // 8 gaussian slots per block
    const int s = t & 31;                  // 32-way j partition per gaussian
    const int i = blockIdx.x * 8 + g;      // 512 blocks x 8 = 4096
    const float di = s_depth[i];

    const float4* s_d4 = (const float4*)s_depth;
    int rank = 0;
    #pragma unroll 8
    for (int k = 0; k < 32; ++k) {
        const int j4 = s + 32 * k;
        const float4 d = s_d4[j4];
        const int j = 4 * j4;
        rank += (d.x < di) || (d.x == di && (j + 0) < i);   // stable argsort
        rank += (d.y < di) || (d.y == di && (j + 1) < i);
        rank += (d.z < di) || (d.z == di && (j + 2) < i);
        rank += (d.w < di) || (d.w == di && (j + 3) < i);
    }
    rank += __shfl_xor(rank, 1);
    rank += __shfl_xor(rank, 2);
    rank += __shfl_xor(rank, 4);
    rank += __shfl_xor(rank, 8);
    rank += __shfl_xor(rank, 16);

    if (s == 0) {
        const float px = pos2d[i * 3 + 0];
        const float py = pos2d[i * 3 + 1];
        const float a = cov2d[i * 4 + 0];
        const float b = cov2d[i * 4 + 1];
        const float c = cov2d[i * 4 + 2];
        const float d = cov2d[i * 4 + 3];

        const float trace = a + d;
        const float det = a * d - b * c;
        const float tmp = trace * trace - 4.0f * det;
        const float term2 = 0.5f * sqrtf(fmaxf(tmp, 0.0f));
        const float radius = 3.0f * sqrtf(fmaxf(0.5f * trace - term2, 0.5f * trace + term2));
        const float inv_det = 1.0f / det;
        const float ia  = d * inv_det;
        const float ibc = (-b * inv_det) + (-c * inv_det);  // match ref's ib+ic rounding
        const float idd = a * inv_det;

        const float op = opacity[i];
        const float cr = fmaxf(color[i * 3 + 0] + 0.5f, 0.0f);
        const float cg = fmaxf(color[i * 3 + 1] + 0.5f, 0.0f);
        const float cb = fmaxf(color[i * 3 + 2] + 0.5f, 0.0f);

        // Tile-overlap bitmask, bit (tx*8+ty); comparisons IDENTICAL to the
        // reference cull so the listed set matches exactly.
        unsigned int xm = 0, ym = 0;
        #pragma unroll
        for (int tc = 0; tc < 8; ++tc) {
            const float lo = (float)(tc * TL_);
            if ((px + radius >= lo) && (px - radius < lo + (float)TL_)) xm |= 1u << tc;
            if ((py + radius >= lo) && (py - radius < lo + (float)TL_)) ym |= 1u << tc;
        }
        unsigned long long m = 0ull;
        #pragma unroll
        for (int tc = 0; tc < 8; ++tc)
            if (xm & (1u << tc)) m |= (unsigned long long)ym << (8 * tc);

        a4[rank] = make_float4(px, py, -0.5f * ia * LOG2E, -0.5f * ibc * LOG2E);
        b4[rank] = make_float4(-0.5f * idd * LOG2E, __log2f(op), cr, cg);
        c1[rank] = cb;
        tmask[rank] = m;
    }
}

__global__ __launch_bounds__(256, 2)
void gs_render(const float4* __restrict__ a4,
               const float4* __restrict__ b4,
               const float* __restrict__ c1,
               const unsigned long long* __restrict__ tmask,
               float* __restrict__ out) {
    // 512 blocks x 256 threads. Block covers 8 px in X, 64 in Y (512 px).
    // Waves 0-1: px columns {0-3,4-7} x depth-seg0; waves 2-3: same px x
    // depth-seg1. End merge: C = C0 + T0*C1 per pixel via LDS.
    __shared__ unsigned short s_list[N_G];
    __shared__ int s_wcnt[4];
    __shared__ __align__(16) float4 s_a0[CHUNK], s_a1[CHUNK];
    __shared__ __align__(16) float4 s_b0[CHUNK], s_b1[CHUNK];
    __shared__ float s_c0[CHUNK], s_c1[CHUNK];
    __shared__ __align__(16) float4 s_comb[512];   // seg1 results (R,G,B,T)

    const int id = blockIdx.x;
    const int sub  = id >> 6;              // 0..7 (X octant)
    const int tile = ((id & 63) * 21 + sub * 11) & 63;
    const int tx = tile >> 3;
    const int ty = tile & 7;
    const int t = threadIdx.x;
    const int wave = t >> 6;
    const int lane = t & 63;

    // ---- cull via tile mask: 2-pass cross-wave-stable compaction, wave w
    //      owns g in [w*1024,(w+1)*1024) so concatenated segments stay
    //      depth-ordered.
    unsigned int bits = 0;
    int wcnt = 0;
    #pragma unroll 4
    for (int it = 0; it < 16; ++it) {
        const int g = wave * 1024 + it * 64 + lane;
        const bool m = (tmask[g] >> tile) & 1ull;
        bits |= (m ? 1u : 0u) << it;
        wcnt += __popcll(__ballot(m));
    }
    if (lane == 0) s_wcnt[wave] = wcnt;
    __syncthreads();
    const int c0 = s_wcnt[0], c1_ = s_wcnt[1], c2 = s_wcnt[2], c3 = s_wcnt[3];
    const int total = c0 + c1_ + c2 + c3;
    int base = (wave > 0 ? c0 : 0) + (wave > 1 ? c1_ : 0) + (wave > 2 ? c2 : 0);
    #pragma unroll 4
    for (int it = 0; it < 16; ++it) {
        const bool m = (bits >> it) & 1u;
        const unsigned long long bal = __ballot(m);
        const int prefix = __popcll(bal & ((1ULL << lane) - 1ULL));
        if (m) s_list[base + prefix] = (unsigned short)(wave * 1024 + it * 64 + lane);
        base += __popcll(bal);
    }
    // barrier before first s_list read is the chunk-loop-top __syncthreads

    const int h      = total >> 1;         // seg0 = [0,h), seg1 = [h,total)
    const int maxlen = total - h;          // >= h

    const int segB = wave >> 1;            // 0: seg0 waves, 1: seg1 waves
    const int xw   = wave & 1;             // X column-group within block
    const int X0 = tx * TL_ + sub * 8 + xw * 4;
    const int Y  = ty * TL_ + lane;
    const float fX = (float)X0;
    const float fY = (float)Y;

    const float4* sa = segB ? s_a1 : s_a0;
    const float4* sb = segB ? s_b1 : s_b0;
    const float*  sc = segB ? s_c1 : s_c0;
    const int seglen = segB ? (total - h) : h;

    float T0 = 1.f, T1 = 1.f, T2 = 1.f, T3 = 1.f;
    float R0 = 0.f, G0 = 0.f, B0 = 0.f;
    float R1 = 0.f, G1 = 0.f, B1 = 0.f;
    float R2 = 0.f, G2 = 0.f, B2 = 0.f;
    float R3 = 0.f, G3 = 0.f, B3 = 0.f;

    for (int cb_ = 0; cb_ < maxlen; cb_ += CHUNK) {
        __syncthreads();   // protect s_list (1st iter) / staging reuse
        {
            const int gi0 = cb_ + t;           // seg0 chunk entry
            if (gi0 < h) {
                const int g = s_list[gi0];
                s_a0[t] = a4[g]; s_b0[t] = b4[g]; s_c0[t] = c1[g];
            }
            const int gi1 = h + cb_ + t;       // seg1 chunk entry
            if (gi1 < total) {
                const int g = s_list[gi1];
                s_a1[t] = a4[g]; s_b1[t] = b4[g]; s_c1[t] = c1[g];
            }
        }
        __syncthreads();

        const int n = min(CHUNK, seglen - cb_);    // may be <= 0 (odd total)
        #pragma unroll 4
        for (int k = 0; k < n; ++k) {
            const float4 A  = sa[k];   // px, py, qa, qb
            const float4 Bv = sb[k];   // qc, lb, cr, cg
            const float cbv = sc[k];
            const float dy   = fY - A.y;
            const float qbdy = A.w * dy;
            const float bse  = Bv.x * dy * dy + Bv.y;        // qc*dy^2 + lb
            const float dx0  = fX - A.x;
#define PX_BLEND(i, T, Rr, Gg, Bb)                                            \
            {                                                                 \
                const float dx = dx0 + (float)i;                              \
                const float q = (A.z * dx + qbdy) * dx + bse;                 \
                const float e = exp2f(q);                                     \
                const float alpha = __builtin_amdgcn_fmed3f(e, 0.01f, 0.99f); \
                const float w_ = alpha * T;                                   \
                Rr += w_ * Bv.z; Gg += w_ * Bv.w; Bb += w_ * cbv;             \
                T -= w_;                                                      \
            }
            PX_BLEND(0, T0, R0, G0, B0)
            PX_BLEND(1, T1, R1, G1, B1)
            PX_BLEND(2, T2, R2, G2, B2)
            PX_BLEND(3, T3, R3, G3, B3)
#undef PX_BLEND
        }
    }

    // ---- merge: seg1 waves publish (R,G,B,T); seg0 waves compose + store.
    const int pxb = xw * 4;                 // column group 0..7 within block
    if (segB) {
        s_comb[(pxb + 0) * 64 + lane] = make_float4(R0, G0, B0, T0);
        s_comb[(pxb + 1) * 64 + lane] = make_float4(R1, G1, B1, T1);
        s_comb[(pxb + 2) * 64 + lane] = make_float4(R2, G2, B2, T2);
        s_comb[(pxb + 3) * 64 + lane] = make_float4(R3, G3, B3, T3);
    }
    __syncthreads();
    if (!segB) {
#define PX_OUT(i, T, Rr, Gg, Bb)                                              \
        {                                                                     \
            const float4 cB = s_comb[(pxb + i) * 64 + lane];                  \
            const int o = ((X0 + i) * W_IMG + Y) * 3;                         \
            out[o + 0] = Rr + T * cB.x;                                       \
            out[o + 1] = Gg + T * cB.y;                                       \
            out[o + 2] = Bb + T * cB.z;                                       \
        }
        PX_OUT(0, T0, R0, G0, B0)
        PX_OUT(1, T1, R1, G1, B1)
        PX_OUT(2, T2, R2, G2, B2)
        PX_OUT(3, T3, R3, G3, B3)
#undef PX_OUT
    }
}

extern "C" void kernel_launch(void* const* d_in, const int* in_sizes, int n_in,
                              void* d_out, int out_size, void* d_ws, size_t ws_size,
                              hipStream_t stream) {
    const float* pos2d   = (const float*)d_in[0];
    const float* cov2d   = (const float*)d_in[1];
    const float* opacity = (const float*)d_in[2];
    const float* color   = (const float*)d_in[3];
    float* out = (float*)d_out;

    char* ws = (char*)d_ws;
    float4* a4 = (float4*)(ws);
    float4* b4 = (float4*)(ws + 65536);
    float*  c1 = (float*)(ws + 131072);
    unsigned long long* tm = (unsigned long long*)(ws + 147456);

    gs_preprocess<<<N_G / 8, 256, 0, stream>>>(pos2d, cov2d, opacity, color,
                                               a4, b4, c1, tm);
    gs_render<<<NTILES * 8, 256, 0, stream>>>(a4, b4, c1, tm, out);
}

// Round 7
// 33.991 us; speedup vs baseline: 1.5844x; 1.1665x over previous
//
#include <hip/hip_runtime.h>

// 2D Gaussian splatting renderer, MI355X. R10.
// N=4096 gaussians, 512x512x3 fp32 image, 64 tiles of 64x64 px.
//
// R10 theory: R5 (26.4us render) vs R9 (28.6us) falsified the LDS-broadcast
// cost model (halving wave-iters gained nothing). Binding terms: per-px VALU
// floor (10 instr/px x 98M px-blends ~ 12.5us), barrier-coupled scattered
// staging, heavy-tile serial path. Note: ref clamps alpha >= 0.01 for EVERY
// in-tile gaussian -> px-blend count is irreducible; make each px-blend
// cheaper and the path less serial:
//  - packed fp32: pixels are independent (serial chain is over gaussians) ->
//    float2 pairs via __builtin_elementwise_fma -> v_pk_fma_f32 (CDNA
//    full-rate packed): ~10 -> ~6 instr/px
//  - P=8 px/lane, 4 contiguous depth segments/block (blend associative:
//    C = Ca + Ta*Cb): 512 blocks x 256 thr, wave w = seg w of same 8x64 px
//    patch; 8 waves/CU kept (R8 lesson); wave-iters 384k -> 192k
//  - ZERO barriers in blend loop: each wave self-stages its own 64-gaussian
//    chunk (global->VGPR->own LDS buf, prefetch next chunk under current
//    chunk's math); end merge (3 composes/px) via LDS + 1 barrier
// Per-px arithmetic sequence identical to R9 -> absmax unchanged.

#define N_G    4096
#define W_IMG  512
#define TL_    64
#define NTILES 64
#define LOG2E  1.44269504088896340736f

typedef float v2f __attribute__((ext_vector_type(2)));

// ws layout (bytes):
//   [0,      65536) : float4 a4[N_G] = {px, py, qa, qb}   (depth-sorted)
//                     qa = -0.5*ia*log2e, qb = -0.5*ibc*log2e
//   [65536, 131072) : float4 b4[N_G] = {qc, lb, cr, cg}
//                     qc = -0.5*idd*log2e, lb = log2(op)
//   [131072,147456) : float  c1[N_G]  = cb
//   [147456,180224) : u64    tmask[N_G] = tile-overlap bitmask (bit tx*8+ty)

__global__ __launch_bounds__(256)
void gs_preprocess(const float* __restrict__ pos2d,
                   const float* __restrict__ cov2d,
                   const float* __restrict__ opacity,
                   const float* __restrict__ color,
                   float4* __restrict__ a4,
                   float4* __restrict__ b4,
                   float* __restrict__ c1,
                   unsigned long long* __restrict__ tmask) {
    __shared__ __align__(16) float s_depth[N_G];
    const int t = threadIdx.x;

    for (int k = t; k < N_G; k += 256)
        s_depth[k] = pos2d[k * 3 + 2];
    __syncthreads();

    const int g = t >> 5;                  // 8 gaussian slots per block
    const int s = t & 31;                  // 32-way j partition per gaussian
    const int i = blockIdx.x * 8 + g;      // 512 blocks x 8 = 4096
    const float di = s_depth[i];

    const float4* s_d4 = (const float4*)s_depth;
    int rank = 0;
    #pragma unroll 8
    for (int k = 0; k < 32; ++k) {
        const int j4 = s + 32 * k;
        const float4 d = s_d4[j4];
        const int j = 4 * j4;
        rank += (d.x < di) || (d.x == di && (j + 0) < i);   // stable argsort
        rank += (d.y < di) || (d.y == di && (j + 1) < i);
        rank += (d.z < di) || (d.z == di && (j + 2) < i);
        rank += (d.w < di) || (d.w == di && (j + 3) < i);
    }
    rank += __shfl_xor(rank, 1);
    rank += __shfl_xor(rank, 2);
    rank += __shfl_xor(rank, 4);
    rank += __shfl_xor(rank, 8);
    rank += __shfl_xor(rank, 16);

    if (s == 0) {
        const float px = pos2d[i * 3 + 0];
        const float py = pos2d[i * 3 + 1];
        const float a = cov2d[i * 4 + 0];
        const float b = cov2d[i * 4 + 1];
        const float c = cov2d[i * 4 + 2];
        const float d = cov2d[i * 4 + 3];

        const float trace = a + d;
        const float det = a * d - b * c;
        const float tmp = trace * trace - 4.0f * det;
        const float term2 = 0.5f * sqrtf(fmaxf(tmp, 0.0f));
        const float radius = 3.0f * sqrtf(fmaxf(0.5f * trace - term2, 0.5f * trace + term2));
        const float inv_det = 1.0f / det;
        const float ia  = d * inv_det;
        const float ibc = (-b * inv_det) + (-c * inv_det);  // match ref's ib+ic rounding
        const float idd = a * inv_det;

        const float op = opacity[i];
        const float cr = fmaxf(color[i * 3 + 0] + 0.5f, 0.0f);
        const float cg = fmaxf(color[i * 3 + 1] + 0.5f, 0.0f);
        const float cb = fmaxf(color[i * 3 + 2] + 0.5f, 0.0f);

        // Tile-overlap bitmask, bit (tx*8+ty); comparisons IDENTICAL to the
        // reference cull so the listed set matches exactly.
        unsigned int xm = 0, ym = 0;
        #pragma unroll
        for (int tc = 0; tc < 8; ++tc) {
            const float lo = (float)(tc * TL_);
            if ((px + radius >= lo) && (px - radius < lo + (float)TL_)) xm |= 1u << tc;
            if ((py + radius >= lo) && (py - radius < lo + (float)TL_)) ym |= 1u << tc;
        }
        unsigned long long m = 0ull;
        #pragma unroll
        for (int tc = 0; tc < 8; ++tc)
            if (xm & (1u << tc)) m |= (unsigned long long)ym << (8 * tc);

        a4[rank] = make_float4(px, py, -0.5f * ia * LOG2E, -0.5f * ibc * LOG2E);
        b4[rank] = make_float4(-0.5f * idd * LOG2E, __log2f(op), cr, cg);
        c1[rank] = cb;
        tmask[rank] = m;
    }
}

__global__ __launch_bounds__(256, 2)
void gs_render(const float4* __restrict__ a4,
               const float4* __restrict__ b4,
               const float* __restrict__ c1,
               const unsigned long long* __restrict__ tmask,
               float* __restrict__ out) {
    // 512 blocks x 256 threads. Block covers 8 px in X, 64 in Y (512 px).
    // Wave w (0..3) processes depth-segment w of the tile list over the SAME
    // 512 px (8 px/lane, lane = Y). End merge composes the 4 segments.
    __shared__ unsigned short s_list[N_G];
    __shared__ int s_wcnt[4];
    __shared__ __align__(16) float4 s_wa[4][64];   // per-wave staged a4 chunk
    __shared__ __align__(16) float4 s_wb[4][64];   // per-wave staged b4 chunk
    __shared__ float s_wc[4][64];                  // per-wave staged cb chunk
    __shared__ __align__(16) float4 s_m[3][512];   // seg1..3 results (R,G,B,T)

    const int id = blockIdx.x;
    const int sub  = id >> 6;              // 0..7 (X octant)
    const int tile = ((id & 63) * 21 + sub * 11) & 63;
    const int tx = tile >> 3;
    const int ty = tile & 7;
    const int t = threadIdx.x;
    const int wave = t >> 6;
    const int lane = t & 63;

    // ---- cull via tile mask: 2-pass cross-wave-stable compaction, wave w
    //      owns g in [w*1024,(w+1)*1024) so concatenated segments stay
    //      depth-ordered.
    unsigned int bits = 0;
    int wcnt = 0;
    #pragma unroll 4
    for (int it = 0; it < 16; ++it) {
        const int g = wave * 1024 + it * 64 + lane;
        const bool m = (tmask[g] >> tile) & 1ull;
        bits |= (m ? 1u : 0u) << it;
        wcnt += __popcll(__ballot(m));
    }
    if (lane == 0) s_wcnt[wave] = wcnt;
    __syncthreads();
    const int c0 = s_wcnt[0], c1_ = s_wcnt[1], c2 = s_wcnt[2], c3 = s_wcnt[3];
    const int total = c0 + c1_ + c2 + c3;
    int base = (wave > 0 ? c0 : 0) + (wave > 1 ? c1_ : 0) + (wave > 2 ? c2 : 0);
    #pragma unroll 4
    for (int it = 0; it < 16; ++it) {
        const bool m = (bits >> it) & 1u;
        const unsigned long long bal = __ballot(m);
        const int prefix = __popcll(bal & ((1ULL << lane) - 1ULL));
        if (m) s_list[base + prefix] = (unsigned short)(wave * 1024 + it * 64 + lane);
        base += __popcll(bal);
    }
    __syncthreads();   // s_list complete; no further barriers until merge

    // ---- this wave's contiguous depth segment
    const int s0 = (wave * total) >> 2;
    const int s1 = ((wave + 1) * total) >> 2;

    const int X0 = tx * TL_ + sub * 8;
    const int Y  = ty * TL_ + lane;
    const float fY = (float)Y;

    // pixel-pair X coordinates (pairs over X: (0,1),(2,3),(4,5),(6,7))
    const v2f fX0 = {(float)(X0 + 0), (float)(X0 + 1)};
    const v2f fX1 = {(float)(X0 + 2), (float)(X0 + 3)};
    const v2f fX2 = {(float)(X0 + 4), (float)(X0 + 5)};
    const v2f fX3 = {(float)(X0 + 6), (float)(X0 + 7)};

    v2f R0 = {0.f, 0.f}, R1 = R0, R2 = R0, R3 = R0;
    v2f G0 = R0, G1 = R0, G2 = R0, G3 = R0;
    v2f B0 = R0, B1 = R0, B2 = R0, B3 = R0;
    v2f T0 = {1.f, 1.f}, T1 = T0, T2 = T0, T3 = T0;

    float4* const wa = s_wa[wave];
    float4* const wb = s_wb[wave];
    float*  const wc = s_wc[wave];

    // prologue: load first chunk (scattered gather, global->VGPR)
    float4 va, vb;
    float vc = 0.f;
    if (s0 + lane < s1) {
        const int g = s_list[s0 + lane];
        va = a4[g]; vb = b4[g]; vc = c1[g];
    }

    for (int c = s0; c < s1; c += 64) {
        const int n = min(64, s1 - c);
        // stage current chunk into this wave's own LDS buffer
        if (lane < n) { wa[lane] = va; wb[lane] = vb; wc[lane] = vc; }
        // prefetch next chunk (hidden under this chunk's math)
        const int cn = c + 64;
        if (cn + lane < s1) {
            const int g = s_list[cn + lane];
            va = a4[g]; vb = b4[g]; vc = c1[g];
        }
        // blend (LDS broadcast reads, same-wave RAW handled by lgkmcnt)
        #pragma unroll 4
        for (int k = 0; k < n; ++k) {
            const float4 A  = wa[k];   // px, py, qa, qb
            const float4 Bv = wb[k];   // qc, lb, cr, cg
            const float cbv = wc[k];

            const float dy   = fY - A.y;
            const float qbdy = A.w * dy;
            const float bse  = Bv.x * dy * dy + Bv.y;      // qc*dy^2 + lb
            const v2f az2 = {A.z, A.z};
            const v2f ax2 = {A.x, A.x};
            const v2f qb2 = {qbdy, qbdy};
            const v2f bs2 = {bse, bse};
            const v2f lo2 = {0.01f, 0.01f};
            const v2f hi2 = {0.99f, 0.99f};
            const v2f cr2 = {Bv.z, Bv.z};
            const v2f cg2 = {Bv.w, Bv.w};
            const v2f cb2 = {cbv, cbv};
#define PX_PAIR(FXP, Tp, Rp, Gp, Bp)                                          \
            {                                                                 \
                const v2f dx = FXP - ax2;                                     \
                v2f q = __builtin_elementwise_fma(az2, dx, qb2);              \
                q = __builtin_elementwise_fma(q, dx, bs2);                    \
                v2f e;                                                        \
                e.x = exp2f(q.x); e.y = exp2f(q.y);                           \
                v2f al;                                                       \
                al.x = __builtin_amdgcn_fmed3f(e.x, lo2.x, hi2.x);            \
                al.y = __builtin_amdgcn_fmed3f(e.y, lo2.y, hi2.y);            \
                const v2f w_ = al * Tp;                                       \
                Rp = __builtin_elementwise_fma(w_, cr2, Rp);                  \
                Gp = __builtin_elementwise_fma(w_, cg2, Gp);                  \
                Bp = __builtin_elementwise_fma(w_, cb2, Bp);                  \
                Tp = Tp - w_;                                                 \
            }
            PX_PAIR(fX0, T0, R0, G0, B0)
            PX_PAIR(fX1, T1, R1, G1, B1)
            PX_PAIR(fX2, T2, R2, G2, B2)
            PX_PAIR(fX3, T3, R3, G3, B3)
#undef PX_PAIR
        }
    }

    // ---- merge: waves 1-3 publish (R,G,B,T) per px; wave 0 composes+stores.
    if (wave != 0) {
        float4* const m = s_m[wave - 1];
#define PUB(j, Tp, Rp, Gp, Bp)                                                \
        m[(2*j + 0) * 64 + lane] = make_float4(Rp.x, Gp.x, Bp.x, Tp.x);       \
        m[(2*j + 1) * 64 + lane] = make_float4(Rp.y, Gp.y, Bp.y, Tp.y);
        PUB(0, T0, R0, G0, B0)
        PUB(1, T1, R1, G1, B1)
        PUB(2, T2, R2, G2, B2)
        PUB(3, T3, R3, G3, B3)
#undef PUB
    }
    __syncthreads();
    if (wave == 0) {
#define OUT_PX(i, tv, rv, gv, bv)                                             \
        {                                                                     \
            const int p = (i) * 64 + lane;                                    \
            const float4 m1 = s_m[0][p];                                      \
            const float4 m2 = s_m[1][p];                                      \
            const float4 m3 = s_m[2][p];                                      \
            float r = m2.x + m2.w * m3.x;                                     \
            float g = m2.y + m2.w * m3.y;                                     \
            float b = m2.z + m2.w * m3.z;                                     \
            r = m1.x + m1.w * r;                                              \
            g = m1.y + m1.w * g;                                              \
            b = m1.z + m1.w * b;                                              \
            const int o = ((X0 + (i)) * W_IMG + Y) * 3;                       \
            out[o + 0] = rv + tv * r;                                         \
            out[o + 1] = gv + tv * g;                                         \
            out[o + 2] = bv + tv * b;                                         \
        }
        OUT_PX(0, T0.x, R0.x, G0.x, B0.x)
        OUT_PX(1, T0.y, R0.y, G0.y, B0.y)
        OUT_PX(2, T1.x, R1.x, G1.x, B1.x)
        OUT_PX(3, T1.y, R1.y, G1.y, B1.y)
        OUT_PX(4, T2.x, R2.x, G2.x, B2.x)
        OUT_PX(5, T2.y, R2.y, G2.y, B2.y)
        OUT_PX(6, T3.x, R3.x, G3.x, B3.x)
        OUT_PX(7, T3.y, R3.y, G3.y, B3.y)
#undef OUT_PX
    }
}

extern "C" void kernel_launch(void* const* d_in, const int* in_sizes, int n_in,
                              void* d_out, int out_size, void* d_ws, size_t ws_size,
                              hipStream_t stream) {
    const float* pos2d   = (const float*)d_in[0];
    const float* cov2d   = (const float*)d_in[1];
    const float* opacity = (const float*)d_in[2];
    const float* color   = (const float*)d_in[3];
    float* out = (float*)d_out;

    char* ws = (char*)d_ws;
    float4* a4 = (float4*)(ws);
    float4* b4 = (float4*)(ws + 65536);
    float*  c1 = (float*)(ws + 131072);
    unsigned long long* tm = (unsigned long long*)(ws + 147456);

    gs_preprocess<<<N_G / 8, 256, 0, stream>>>(pos2d, cov2d, opacity, color,
                                               a4, b4, c1, tm);
    gs_render<<<NTILES * 8, 256, 0, stream>>>(a4, b4, c1, tm, out);
}

// Round 8
// 33.591 us; speedup vs baseline: 1.6033x; 1.0119x over previous
//
#include <hip/hip_runtime.h>

// 2D Gaussian splatting renderer, MI355X. R11.
// N=4096 gaussians, 512x512x3 fp32 image, 64 tiles of 64x64 px.
//
// R11 theory: R10 (dur 34, render ~23us) runs at only 2 waves/SIMD; pipe
// model (VALU 7.8us, LDS 9.4us, trans 5us on separate pipes) says ~10-12us
// is achievable with real latency hiding. With 256-thr blocks the 512-block
// grid pins 2 blocks/CU regardless of launch_bounds; bigger grids inflate
// wave-iters. Escape: 512-THREAD blocks, 512 blocks -> 16 waves/CU
// (4/SIMD) at CONSTANT wave-iters (192k): 8 blocks/tile x 8 depth-segments
// per block, each wave = total/8 iters over the same 8x64-px patch.
//  - blend inner loop byte-identical to R10 (packed v2f, exp2, med3)
//  - 3-round tree merge of 8 segments (7 composes, 3 barriers, 32KB bufs;
//    total LDS 59.4KB < 64KB, 2 blocks/CU)
//  - launch_bounds(512,4) caps VGPR at 128 (est ~100, no spill)
//  - heavy-tile per-wave path halves: 600-tile -> 75 iters/wave; segments
//    equal length -> perfect intra-block balance

#define N_G    4096
#define W_IMG  512
#define TL_    64
#define NTILES 64
#define LOG2E  1.44269504088896340736f

typedef float v2f __attribute__((ext_vector_type(2)));

// ws layout (bytes):
//   [0,      65536) : float4 a4[N_G] = {px, py, qa, qb}   (depth-sorted)
//                     qa = -0.5*ia*log2e, qb = -0.5*ibc*log2e
//   [65536, 131072) : float4 b4[N_G] = {qc, lb, cr, cg}
//                     qc = -0.5*idd*log2e, lb = log2(op)
//   [131072,147456) : float  c1[N_G]  = cb
//   [147456,180224) : u64    tmask[N_G] = tile-overlap bitmask (bit tx*8+ty)

__global__ __launch_bounds__(256)
void gs_preprocess(const float* __restrict__ pos2d,
                   const float* __restrict__ cov2d,
                   const float* __restrict__ opacity,
                   const float* __restrict__ color,
                   float4* __restrict__ a4,
                   float4* __restrict__ b4,
                   float* __restrict__ c1,
                   unsigned long long* __restrict__ tmask) {
    __shared__ __align__(16) float s_depth[N_G];
    const int t = threadIdx.x;

    for (int k = t; k < N_G; k += 256)
        s_depth[k] = pos2d[k * 3 + 2];
    __syncthreads();

    const int g = t >> 5;                  // 8 gaussian slots per block
    const int s = t & 31;                  // 32-way j partition per gaussian
    const int i = blockIdx.x * 8 + g;      // 512 blocks x 8 = 4096
    const float di = s_depth[i];

    const float4* s_d4 = (const float4*)s_depth;
    int rank = 0;
    #pragma unroll 8
    for (int k = 0; k < 32; ++k) {
        const int j4 = s + 32 * k;
        const float4 d = s_d4[j4];
        const int j = 4 * j4;
        rank += (d.x < di) || (d.x == di && (j + 0) < i);   // stable argsort
        rank += (d.y < di) || (d.y == di && (j + 1) < i);
        rank += (d.z < di) || (d.z == di && (j + 2) < i);
        rank += (d.w < di) || (d.w == di && (j + 3) < i);
    }
    rank += __shfl_xor(rank, 1);
    rank += __shfl_xor(rank, 2);
    rank += __shfl_xor(rank, 4);
    rank += __shfl_xor(rank, 8);
    rank += __shfl_xor(rank, 16);

    if (s == 0) {
        const float px = pos2d[i * 3 + 0];
        const float py = pos2d[i * 3 + 1];
        const float a = cov2d[i * 4 + 0];
        const float b = cov2d[i * 4 + 1];
        const float c = cov2d[i * 4 + 2];
        const float d = cov2d[i * 4 + 3];

        const float trace = a + d;
        const float det = a * d - b * c;
        const float tmp = trace * trace - 4.0f * det;
        const float term2 = 0.5f * sqrtf(fmaxf(tmp, 0.0f));
        const float radius = 3.0f * sqrtf(fmaxf(0.5f * trace - term2, 0.5f * trace + term2));
        const float inv_det = 1.0f / det;
        const float ia  = d * inv_det;
        const float ibc = (-b * inv_det) + (-c * inv_det);  // match ref's ib+ic rounding
        const float idd = a * inv_det;

        const float op = opacity[i];
        const float cr = fmaxf(color[i * 3 + 0] + 0.5f, 0.0f);
        const float cg = fmaxf(color[i * 3 + 1] + 0.5f, 0.0f);
        const float cb = fmaxf(color[i * 3 + 2] + 0.5f, 0.0f);

        // Tile-overlap bitmask, bit (tx*8+ty); comparisons IDENTICAL to the
        // reference cull so the listed set matches exactly.
        unsigned int xm = 0, ym = 0;
        #pragma unroll
        for (int tc = 0; tc < 8; ++tc) {
            const float lo = (float)(tc * TL_);
            if ((px + radius >= lo) && (px - radius < lo + (float)TL_)) xm |= 1u << tc;
            if ((py + radius >= lo) && (py - radius < lo + (float)TL_)) ym |= 1u << tc;
        }
        unsigned long long m = 0ull;
        #pragma unroll
        for (int tc = 0; tc < 8; ++tc)
            if (xm & (1u << tc)) m |= (unsigned long long)ym << (8 * tc);

        a4[rank] = make_float4(px, py, -0.5f * ia * LOG2E, -0.5f * ibc * LOG2E);
        b4[rank] = make_float4(-0.5f * idd * LOG2E, __log2f(op), cr, cg);
        c1[rank] = cb;
        tmask[rank] = m;
    }
}

__global__ __launch_bounds__(512, 4)
void gs_render(const float4* __restrict__ a4,
               const float4* __restrict__ b4,
               const float* __restrict__ c1,
               const unsigned long long* __restrict__ tmask,
               float* __restrict__ out) {
    // 512 blocks x 512 threads (8 waves). Block covers 8 px in X, 64 in Y.
    // All 8 waves share the SAME 512-px patch; wave w = depth-segment w.
    // 3-round tree merge at the end. 16 waves/CU (4/SIMD).
    __shared__ unsigned short s_list[N_G];
    __shared__ int s_wcnt[8];
    __shared__ __align__(16) float4 s_wa[8][64];   // per-wave staged a4 chunk
    __shared__ __align__(16) float4 s_wb[8][64];   // per-wave staged b4 chunk
    __shared__ float s_wc[8][64];                  // per-wave staged cb chunk
    __shared__ __align__(16) float4 s_m[4][512];   // merge buffers (R,G,B,T)

    const int id = blockIdx.x;
    const int sub  = id >> 6;              // 0..7 (X octant)
    const int tile = ((id & 63) * 21 + sub * 11) & 63;
    const int tx = tile >> 3;
    const int ty = tile & 7;
    const int t = threadIdx.x;
    const int wave = t >> 6;               // 0..7
    const int lane = t & 63;

    // ---- cull via tile mask: 2-pass cross-wave-stable compaction, wave w
    //      owns g in [w*512,(w+1)*512) so concatenated segments stay
    //      depth-ordered.
    unsigned int bits = 0;
    int wcnt = 0;
    #pragma unroll 4
    for (int it = 0; it < 8; ++it) {
        const int g = wave * 512 + it * 64 + lane;
        const bool m = (tmask[g] >> tile) & 1ull;
        bits |= (m ? 1u : 0u) << it;
        wcnt += __popcll(__ballot(m));
    }
    if (lane == 0) s_wcnt[wave] = wcnt;
    __syncthreads();
    int total = 0, base = 0;
    #pragma unroll
    for (int w = 0; w < 8; ++w) {
        const int c = s_wcnt[w];
        total += c;
        if (w < wave) base += c;
    }
    #pragma unroll 4
    for (int it = 0; it < 8; ++it) {
        const bool m = (bits >> it) & 1u;
        const unsigned long long bal = __ballot(m);
        const int prefix = __popcll(bal & ((1ULL << lane) - 1ULL));
        if (m) s_list[base + prefix] = (unsigned short)(wave * 512 + it * 64 + lane);
        base += __popcll(bal);
    }
    __syncthreads();   // s_list complete; no barriers until merge

    // ---- this wave's contiguous depth segment (equal length, +-1)
    const int s0 = (wave * total) >> 3;
    const int s1 = ((wave + 1) * total) >> 3;

    const int X0 = tx * TL_ + sub * 8;
    const int Y  = ty * TL_ + lane;
    const float fY = (float)Y;

    const v2f fX0 = {(float)(X0 + 0), (float)(X0 + 1)};
    const v2f fX1 = {(float)(X0 + 2), (float)(X0 + 3)};
    const v2f fX2 = {(float)(X0 + 4), (float)(X0 + 5)};
    const v2f fX3 = {(float)(X0 + 6), (float)(X0 + 7)};

    v2f R0 = {0.f, 0.f}, R1 = R0, R2 = R0, R3 = R0;
    v2f G0 = R0, G1 = R0, G2 = R0, G3 = R0;
    v2f B0 = R0, B1 = R0, B2 = R0, B3 = R0;
    v2f T0 = {1.f, 1.f}, T1 = T0, T2 = T0, T3 = T0;

    float4* const wa = s_wa[wave];
    float4* const wb = s_wb[wave];
    float*  const wc = s_wc[wave];

    // prologue: load first chunk (scattered gather, global->VGPR)
    float4 va, vb;
    float vc = 0.f;
    if (s0 + lane < s1) {
        const int g = s_list[s0 + lane];
        va = a4[g]; vb = b4[g]; vc = c1[g];
    }

    for (int c = s0; c < s1; c += 64) {
        const int n = min(64, s1 - c);
        // stage current chunk into this wave's own LDS buffer
        if (lane < n) { wa[lane] = va; wb[lane] = vb; wc[lane] = vc; }
        // prefetch next chunk (hidden under this chunk's math)
        const int cn = c + 64;
        if (cn + lane < s1) {
            const int g = s_list[cn + lane];
            va = a4[g]; vb = b4[g]; vc = c1[g];
        }
        // blend (LDS broadcast reads, same-wave RAW handled by lgkmcnt)
        #pragma unroll 4
        for (int k = 0; k < n; ++k) {
            const float4 A  = wa[k];   // px, py, qa, qb
            const float4 Bv = wb[k];   // qc, lb, cr, cg
            const float cbv = wc[k];

            const float dy   = fY - A.y;
            const float qbdy = A.w * dy;
            const float bse  = Bv.x * dy * dy + Bv.y;      // qc*dy^2 + lb
            const v2f az2 = {A.z, A.z};
            const v2f ax2 = {A.x, A.x};
            const v2f qb2 = {qbdy, qbdy};
            const v2f bs2 = {bse, bse};
            const v2f lo2 = {0.01f, 0.01f};
            const v2f hi2 = {0.99f, 0.99f};
            const v2f cr2 = {Bv.z, Bv.z};
            const v2f cg2 = {Bv.w, Bv.w};
            const v2f cb2 = {cbv, cbv};
#define PX_PAIR(FXP, Tp, Rp, Gp, Bp)                                          \
            {                                                                 \
                const v2f dx = FXP - ax2;                                     \
                v2f q = __builtin_elementwise_fma(az2, dx, qb2);              \
                q = __builtin_elementwise_fma(q, dx, bs2);                    \
                v2f e;                                                        \
                e.x = exp2f(q.x); e.y = exp2f(q.y);                           \
                v2f al;                                                       \
                al.x = __builtin_amdgcn_fmed3f(e.x, lo2.x, hi2.x);            \
                al.y = __builtin_amdgcn_fmed3f(e.y, lo2.y, hi2.y);            \
                const v2f w_ = al * Tp;                                       \
                Rp = __builtin_elementwise_fma(w_, cr2, Rp);                  \
                Gp = __builtin_elementwise_fma(w_, cg2, Gp);                  \
                Bp = __builtin_elementwise_fma(w_, cb2, Bp);                  \
                Tp = Tp - w_;                                                 \
            }
            PX_PAIR(fX0, T0, R0, G0, B0)
            PX_PAIR(fX1, T1, R1, G1, B1)
            PX_PAIR(fX2, T2, R2, G2, B2)
            PX_PAIR(fX3, T3, R3, G3, B3)
#undef PX_PAIR
        }
    }

    // ---- 3-round tree merge: ((0,1),(2,3)),((4,5),(6,7)).
    // publish: write 8 px (R,G,B,T); compose: C += T*Cnext, T *= Tnext.
#define PUBLISH(buf)                                                          \
    {                                                                         \
        (buf)[0 * 64 + lane] = make_float4(R0.x, G0.x, B0.x, T0.x);           \
        (buf)[1 * 64 + lane] = make_float4(R0.y, G0.y, B0.y, T0.y);           \
        (buf)[2 * 64 + lane] = make_float4(R1.x, G1.x, B1.x, T1.x);           \
        (buf)[3 * 64 + lane] = make_float4(R1.y, G1.y, B1.y, T1.y);           \
        (buf)[4 * 64 + lane] = make_float4(R2.x, G2.x, B2.x, T2.x);           \
        (buf)[5 * 64 + lane] = make_float4(R2.y, G2.y, B2.y, T2.y);           \
        (buf)[6 * 64 + lane] = make_float4(R3.x, G3.x, B3.x, T3.x);           \
        (buf)[7 * 64 + lane] = make_float4(R3.y, G3.y, B3.y, T3.y);           \
    }
#define COMPOSE(buf)                                                          \
    {                                                                         \
        _Pragma("unroll")                                                     \
        for (int j = 0; j < 4; ++j) {                                         \
            const float4 m0 = (buf)[(2 * j + 0) * 64 + lane];                 \
            const float4 m1 = (buf)[(2 * j + 1) * 64 + lane];                 \
            const v2f mr = {m0.x, m1.x};                                      \
            const v2f mg = {m0.y, m1.y};                                      \
            const v2f mb = {m0.z, m1.z};                                      \
            const v2f mt = {m0.w, m1.w};                                      \
            v2f* Rj = j == 0 ? &R0 : j == 1 ? &R1 : j == 2 ? &R2 : &R3;       \
            v2f* Gj = j == 0 ? &G0 : j == 1 ? &G1 : j == 2 ? &G2 : &G3;       \
            v2f* Bj = j == 0 ? &B0 : j == 1 ? &B1 : j == 2 ? &B2 : &B3;       \
            v2f* Tj = j == 0 ? &T0 : j == 1 ? &T1 : j == 2 ? &T2 : &T3;       \
            *Rj = __builtin_elementwise_fma(*Tj, mr, *Rj);                    \
            *Gj = __builtin_elementwise_fma(*Tj, mg, *Gj);                    \
            *Bj = __builtin_elementwise_fma(*Tj, mb, *Bj);                    \
            *Tj = *Tj * mt;                                                   \
        }                                                                     \
    }

    // round 1: odd waves publish; even waves compose
    if (wave & 1) PUBLISH(s_m[wave >> 1]);
    __syncthreads();
    if (!(wave & 1)) COMPOSE(s_m[wave >> 1]);
    // round 2: waves 2,6 publish (reuse the buffer each just read)
    if (wave == 2) PUBLISH(s_m[1]);
    if (wave == 6) PUBLISH(s_m[3]);
    __syncthreads();
    if (wave == 0) COMPOSE(s_m[1]);
    if (wave == 4) COMPOSE(s_m[3]);
    // round 3: wave 4 publishes; wave 0 composes + stores
    if (wave == 4) PUBLISH(s_m[3]);
    __syncthreads();
    if (wave == 0) {
        COMPOSE(s_m[3]);
#define OUT_PX(i, tv, rv, gv, bv)                                             \
        {                                                                     \
            const int o = ((X0 + (i)) * W_IMG + Y) * 3;                       \
            out[o + 0] = rv;                                                  \
            out[o + 1] = gv;                                                  \
            out[o + 2] = bv;                                                  \
        }
        OUT_PX(0, T0.x, R0.x, G0.x, B0.x)
        OUT_PX(1, T0.y, R0.y, G0.y, B0.y)
        OUT_PX(2, T1.x, R1.x, G1.x, B1.x)
        OUT_PX(3, T1.y, R1.y, G1.y, B1.y)
        OUT_PX(4, T2.x, R2.x, G2.x, B2.x)
        OUT_PX(5, T2.y, R2.y, G2.y, B2.y)
        OUT_PX(6, T3.x, R3.x, G3.x, B3.x)
        OUT_PX(7, T3.y, R3.y, G3.y, B3.y)
#undef OUT_PX
    }
#undef PUBLISH
#undef COMPOSE
}

extern "C" void kernel_launch(void* const* d_in, const int* in_sizes, int n_in,
                              void* d_out, int out_size, void* d_ws, size_t ws_size,
                              hipStream_t stream) {
    const float* pos2d   = (const float*)d_in[0];
    const float* cov2d   = (const float*)d_in[1];
    const float* opacity = (const float*)d_in[2];
    const float* color   = (const float*)d_in[3];
    float* out = (float*)d_out;

    char* ws = (char*)d_ws;
    float4* a4 = (float4*)(ws);
    float4* b4 = (float4*)(ws + 65536);
    float*  c1 = (float*)(ws + 131072);
    unsigned long long* tm = (unsigned long long*)(ws + 147456);

    gs_preprocess<<<N_G / 8, 256, 0, stream>>>(pos2d, cov2d, opacity, color,
                                               a4, b4, c1, tm);
    gs_render<<<NTILES * 8, 512, 0, stream>>>(a4, b4, c1, tm, out);
}